// Round 4
// baseline (427.123 us; speedup 1.0000x reference)
//
#include <hip/hip_runtime.h>

// Problem constants (from reference setup_inputs)
#define N_   32
#define T_   16
#define C_   128
#define H_   32
#define W_   32
#define CHW  (C_ * H_ * W_)      // 131072
#define CHW4 (CHW / 4)           // 32768 float4 per (n,t) slab

// Native clang vector — required by __builtin_nontemporal_{load,store}
typedef float vf4 __attribute__((ext_vector_type(4)));

__global__ __launch_bounds__(256) void lif_kernel(
    const vf4* __restrict__ x,      // (N, T, CHW/4)
    const vf4* __restrict__ v_init, // (N, CHW/4)
    vf4* __restrict__ out)          // (N, T, CHW/4)
{
    const int idx = blockIdx.x * blockDim.x + threadIdx.x;  // over N*CHW4
    const int n   = idx >> 15;          // idx / CHW4  (CHW4 = 2^15)
    const int rem = idx & (CHW4 - 1);   // idx % CHW4

    // base vf4 index of (n, t=0, rem)
    const long long base = (long long)n * (T_ * CHW4) + rem;

    // Issue v first so waiting on it leaves all 16 x-loads outstanding.
    vf4 v = __builtin_nontemporal_load(&v_init[idx]);

    // Phase 1: issue ALL 16 loads — guarantees 256 B outstanding reads per
    // thread (read-MLP; the old interleaved loop fenced loads behind stores
    // via the shared vmcnt counter).
    vf4 xt[T_];
    #pragma unroll
    for (int t = 0; t < T_; ++t)
        xt[t] = __builtin_nontemporal_load(&x[base + (long long)t * CHW4]);

    // Phase 2: serial v-chain, consuming loads as they arrive
    // (compiler emits vmcnt(15-t) waits). Spike overwrites xt[t] in place.
    #pragma unroll
    for (int t = 0; t < T_; ++t) {
        vf4 e = xt[t];
        vf4 s;
        v.x = v.x * 0.5f + e.x;  s.x = (v.x >= 1.0f) ? 1.0f : 0.0f;  v.x -= s.x;
        v.y = v.y * 0.5f + e.y;  s.y = (v.y >= 1.0f) ? 1.0f : 0.0f;  v.y -= s.y;
        v.z = v.z * 0.5f + e.z;  s.z = (v.z >= 1.0f) ? 1.0f : 0.0f;  v.z -= s.z;
        v.w = v.w * 0.5f + e.w;  s.w = (v.w >= 1.0f) ? 1.0f : 0.0f;  v.w -= s.w;
        xt[t] = s;
    }

    // Phase 3: one same-direction store burst (16 KB/wave) — minimizes
    // DRAM read/write turnaround vs interleaved load/store.
    #pragma unroll
    for (int t = 0; t < T_; ++t)
        __builtin_nontemporal_store(xt[t], &out[base + (long long)t * CHW4]);
}

extern "C" void kernel_launch(void* const* d_in, const int* in_sizes, int n_in,
                              void* d_out, int out_size, void* d_ws, size_t ws_size,
                              hipStream_t stream) {
    const vf4* x  = (const vf4*)d_in[0];   // (N,T,C,H,W) fp32
    const vf4* v0 = (const vf4*)d_in[1];   // (N,C,H,W)  fp32 zeros
    vf4* out      = (vf4*)d_out;           // (N,T,C,H,W) fp32

    const int total4 = N_ * CHW4;          // 1,048,576 threads
    const int block  = 256;
    const int grid   = total4 / block;     // 4096 blocks

    lif_kernel<<<grid, block, 0, stream>>>(x, v0, out);
}